// Round 3
// baseline (742.949 us; speedup 1.0000x reference)
//
#include <hip/hip_runtime.h>

#define M_DIM 8192
#define K_DIM 4096
#define N_DIM 11008
#define BM 256
#define BN 256
#define BK 64
#define TILES_M (M_DIM / BM)     // 32
#define TILES_N (N_DIM / BN)     // 43
#define NT (K_DIM / BK)          // 64
#define NWG (TILES_M * TILES_N)  // 1376 = 8 * 172

typedef __attribute__((ext_vector_type(8))) short bf16x8;
typedef __attribute__((ext_vector_type(4))) float f32x4;
typedef __attribute__((ext_vector_type(8))) unsigned short u16x8;

__device__ __forceinline__ unsigned short f2bf_rne(float f) {
    unsigned int u = __float_as_uint(f);
    unsigned int r = (u + 0x7FFFu + ((u >> 16) & 1u)) >> 16;
    return (unsigned short)r;
}

__device__ __forceinline__ void gload_lds16(const void* g, void* l) {
    __builtin_amdgcn_global_load_lds(
        (const __attribute__((address_space(1))) void*)g,
        (__attribute__((address_space(3))) void*)l, 16, 0, 0);
}

// ---------------- x: fp32 -> bf16 (8 elems / thread) ----------------
__global__ __launch_bounds__(256) void cast_x_kernel(const float* __restrict__ x,
                                                     unsigned short* __restrict__ xb) {
    size_t t = (size_t)blockIdx.x * 256 + threadIdx.x;
    const float4* p = reinterpret_cast<const float4*>(x) + 2 * t;
    float4 a = p[0];
    float4 b = p[1];
    u16x8 o;
    o[0] = f2bf_rne(a.x); o[1] = f2bf_rne(a.y); o[2] = f2bf_rne(a.z); o[3] = f2bf_rne(a.w);
    o[4] = f2bf_rne(b.x); o[5] = f2bf_rne(b.y); o[6] = f2bf_rne(b.z); o[7] = f2bf_rne(b.w);
    *reinterpret_cast<u16x8*>(xb + 8 * t) = o;
}

// ------- weight: per-128-group absmax scale, sign*scale -> bf16 -------
__global__ __launch_bounds__(256) void binarize_w_kernel(const float* __restrict__ w,
                                                         unsigned short* __restrict__ weff) {
    size_t t = (size_t)blockIdx.x * 256 + threadIdx.x;
    size_t group = t >> 5;
    int l32 = (int)(t & 31);
    const float4* src = reinterpret_cast<const float4*>(w + group * 128) + l32;
    float4 v = *src;
    float amax = fmaxf(fmaxf(fabsf(v.x), fabsf(v.y)), fmaxf(fabsf(v.z), fabsf(v.w)));
#pragma unroll
    for (int off = 16; off >= 1; off >>= 1)
        amax = fmaxf(amax, __shfl_xor(amax, off));
    float scale = fmaxf(amax, 1e-8f);
    unsigned short pb = f2bf_rne(scale);
    unsigned short nb = (unsigned short)(pb | 0x8000u);
    ushort4 o;
    o.x = (v.x == 0.0f) ? (unsigned short)0 : ((v.x > 0.0f) ? pb : nb);
    o.y = (v.y == 0.0f) ? (unsigned short)0 : ((v.y > 0.0f) ? pb : nb);
    o.z = (v.z == 0.0f) ? (unsigned short)0 : ((v.z > 0.0f) ? pb : nb);
    o.w = (v.w == 0.0f) ? (unsigned short)0 : ((v.w > 0.0f) ? pb : nb);
    *reinterpret_cast<ushort4*>(weff + group * 128 + (size_t)l32 * 4) = o;
}

// ---------------- GEMM: C[M][N] = Xb[M][K] * Weff[N][K]^T ----------------
// 256x256 tile, BK=64, 8 waves (2Mx4N). 4 phases/K-tile, ONE barrier/phase;
// all ds_reads issued inside the MFMA stream of the previous phase (double
// A/B frag banks); counted vmcnt(2) at q2-end publishes next tile's LDS
// before q3's cross-tile tail reads.
__global__ __launch_bounds__(512, 2) void gemm_bin_kernel(
        const unsigned short* __restrict__ A,   // Xb  [M][K] bf16
        const unsigned short* __restrict__ B,   // Weff[N][K] bf16
        float* __restrict__ C) {
    __shared__ unsigned short lds[2][2][2][8192];  // [buf][A/B][half][128*64]

    const int bid = blockIdx.x;
    const int swz = (bid & 7) * (NWG / 8) + (bid >> 3);   // bijective: NWG % 8 == 0
    const int tm = swz / TILES_N;
    const int tn = swz % TILES_N;

    const int tid = threadIdx.x;
    const int wave = tid >> 6;
    const int lane = tid & 63;
    const int wm = wave >> 2;      // 0..1 -> A half
    const int wn = wave & 3;       // 0..3 -> B half = wn>>1, sub-block = wn&1
    const int l15 = lane & 15;
    const int l4  = lane >> 4;
    const int brow0 = (wn & 1) * 64;

    // ---- staging: linear LDS dest, pre-swizzled global source ----
    const int srow  = tid >> 3;                  // 0..63 (chunk adds +64)
    const int gslot = (tid & 7) ^ (srow & 7);
    const unsigned short* Asrc = A + (size_t)(tm * BM + srow) * K_DIM + gslot * 8;
    const unsigned short* Bsrc = B + (size_t)(tn * BN + srow) * K_DIM + gslot * 8;

    auto stageA = [&](int buf, int half, int kt) {
        const unsigned short* s = Asrc + (size_t)(half * 128) * K_DIM + kt;
        unsigned short* d = &lds[buf][0][half][tid * 8];
        gload_lds16(s, d);
        gload_lds16(s + (size_t)64 * K_DIM, d + 4096);
    };
    auto stageB = [&](int buf, int half, int kt) {
        const unsigned short* s = Bsrc + (size_t)(half * 128) * K_DIM + kt;
        unsigned short* d = &lds[buf][1][half][tid * 8];
        gload_lds16(s, d);
        gload_lds16(s + (size_t)64 * K_DIM, d + 4096);
    };
    auto readfrag = [&](const unsigned short* base, int rowl, int ks) -> bf16x8 {
        return *reinterpret_cast<const bf16x8*>(
            &base[rowl * 64 + (((ks * 4 + l4) ^ (rowl & 7)) * 8)]);
    };

    f32x4 acc[8][4] = {};
    bf16x8 bfA[4][2], bfB[4][2], af0[2][2], af1[2][2];

#define READ_A(DST, BASE, Q)                                                    \
    {                                                                           \
        _Pragma("unroll") for (int r_ = 0; r_ < 2; ++r_) {                      \
            _Pragma("unroll") for (int ks_ = 0; ks_ < 2; ++ks_) {               \
                DST[r_][ks_] = readfrag(BASE, (2 * (Q) + r_) * 16 + l15, ks_);  \
            }                                                                   \
        }                                                                       \
    }
#define READ_B(DST, BASE)                                                       \
    {                                                                           \
        _Pragma("unroll") for (int j_ = 0; j_ < 4; ++j_) {                      \
            _Pragma("unroll") for (int ks_ = 0; ks_ < 2; ++ks_) {               \
                DST[j_][ks_] = readfrag(BASE, brow0 + j_ * 16 + l15, ks_);      \
            }                                                                   \
        }                                                                       \
    }
#define MFMA8(AF, BF, Q, KS)                                                    \
    {                                                                           \
        _Pragma("unroll") for (int r_ = 0; r_ < 2; ++r_) {                      \
            _Pragma("unroll") for (int j_ = 0; j_ < 4; ++j_) {                  \
                acc[2 * (Q) + r_][j_] = __builtin_amdgcn_mfma_f32_16x16x32_bf16(\
                    AF[r_][KS], BF[j_][KS], acc[2 * (Q) + r_][j_], 0, 0, 0);    \
            }                                                                   \
        }                                                                       \
    }

    // ---- prologue: tile0 {A0,A1,B0,B1}->buf0, tile1 {B0,B1}->buf1 ----
    stageA(0, 0, 0); stageA(0, 1, 0);
    stageB(0, 0, 0); stageB(0, 1, 0);
    stageB(1, 0, BK); stageB(1, 1, BK);
    asm volatile("s_waitcnt vmcnt(4)" ::: "memory");   // A(0),B(0) done; B(1) in flight
    __builtin_amdgcn_s_barrier();
    READ_B(bfA, (&lds[0][1][wn >> 1][0]));
    READ_A(af0, (&lds[0][0][wm][0]), 0);

#define KTILE(T, CUR, NXT, BF, BFN)                                             \
    {                                                                           \
        const unsigned short* Ah  = &lds[CUR][0][wm][0];                        \
        const unsigned short* Ahn = &lds[NXT][0][wm][0];                        \
        const unsigned short* Bhn = &lds[NXT][1][wn >> 1][0];                   \
        /* q0 */                                                                \
        if ((T) + 1 < NT) stageA(NXT, 0, ((T) + 1) * BK);                       \
        __builtin_amdgcn_s_setprio(1);                                          \
        MFMA8(af0, BF, 0, 0);                                                   \
        READ_A(af1, Ah, 1);                                                     \
        MFMA8(af0, BF, 0, 1);                                                   \
        __builtin_amdgcn_s_setprio(0);                                          \
        __builtin_amdgcn_s_barrier();                                           \
        /* q1 */                                                                \
        if ((T) + 1 < NT) stageA(NXT, 1, ((T) + 1) * BK);                       \
        __builtin_amdgcn_s_setprio(1);                                          \
        MFMA8(af1, BF, 1, 0);                                                   \
        READ_A(af0, Ah, 2);                                                     \
        MFMA8(af1, BF, 1, 1);                                                   \
        __builtin_amdgcn_s_setprio(0);                                          \
        __builtin_amdgcn_s_barrier();                                           \
        /* q2 */                                                                \
        if ((T) + 2 < NT) stageB(CUR, 0, ((T) + 2) * BK);                       \
        __builtin_amdgcn_s_setprio(1);                                          \
        MFMA8(af0, BF, 2, 0);                                                   \
        READ_A(af1, Ah, 3);                                                     \
        MFMA8(af0, BF, 2, 1);                                                   \
        __builtin_amdgcn_s_setprio(0);                                          \
        if ((T) + 2 < NT) { asm volatile("s_waitcnt vmcnt(2)" ::: "memory"); }  \
        else              { asm volatile("s_waitcnt vmcnt(0)" ::: "memory"); }  \
        __builtin_amdgcn_s_barrier();                                           \
        /* q3: next tile's A(t+1),B(t+1) now published in LDS */                \
        if ((T) + 2 < NT) stageB(CUR, 1, ((T) + 2) * BK);                       \
        __builtin_amdgcn_s_setprio(1);                                          \
        MFMA8(af1, BF, 3, 0);                                                   \
        if ((T) + 1 < NT) { READ_B(BFN, Bhn); READ_A(af0, Ahn, 0); }            \
        MFMA8(af1, BF, 3, 1);                                                   \
        __builtin_amdgcn_s_setprio(0);                                          \
        __builtin_amdgcn_s_barrier();                                           \
    }

#pragma unroll 1
    for (int tt = 0; tt < NT; tt += 2) {
        KTILE(tt,     0, 1, bfA, bfB);
        KTILE(tt + 1, 1, 0, bfB, bfA);
    }

    // ---- epilogue: C/D layout col=lane&15, row=(lane>>4)*4+reg; NT stores ----
    const size_t crow0 = (size_t)tm * BM + wm * 128 + l4 * 4;
    const int ccol0 = tn * BN + wn * 64 + l15;
#pragma unroll
    for (int i = 0; i < 8; ++i) {
#pragma unroll
        for (int j = 0; j < 4; ++j) {
            float* cp = C + (crow0 + i * 16) * N_DIM + ccol0 + j * 16;
#pragma unroll
            for (int r = 0; r < 4; ++r)
                __builtin_nontemporal_store(acc[i][j][r], cp + (size_t)r * N_DIM);
        }
    }
}

extern "C" void kernel_launch(void* const* d_in, const int* in_sizes, int n_in,
                              void* d_out, int out_size, void* d_ws, size_t ws_size,
                              hipStream_t stream) {
    const float* x = (const float*)d_in[0];       // [4,2048,4096] fp32
    const float* w = (const float*)d_in[1];       // [11008,4096] fp32
    float* out = (float*)d_out;                   // [4,2048,11008] fp32

    unsigned short* xb = (unsigned short*)d_ws;                                        // 64 MiB
    unsigned short* weff = (unsigned short*)((char*)d_ws + (size_t)M_DIM * K_DIM * 2); // 86 MiB

    cast_x_kernel<<<(M_DIM * K_DIM / 8) / 256, 256, 0, stream>>>(x, xb);
    binarize_w_kernel<<<(N_DIM * K_DIM / 4) / 256, 256, 0, stream>>>(w, weff);
    gemm_bin_kernel<<<NWG, 512, 0, stream>>>(xb, weff, out);
}